// Round 2
// baseline (133.729 us; speedup 1.0000x reference)
//
#include <hip/hip_runtime.h>
#include <hip/hip_bf16.h>

// STDP via the antisymmetric-kernel identity (verified R6, absmax 9.8e-4):
//   out[q,p] = 4w(1-w) * A_SCALE * sum_{b,t} post_s[b,t,q] * Z[b,t,p]
//   Z = pre_tr - pre_rt;  tr = causal decay scan, rt = anti-causal scan.
//   AT[q][b*128+t] = post_spikes (bf16);  BT[p][b*128+t] = Z (bf16)

typedef __attribute__((ext_vector_type(8))) short bf16x8;
typedef __attribute__((ext_vector_type(4))) float f32x4;

#define GN 2048
#define KTOT 2048
#define A_SCALE (0.01f / 16.0f)
#define FST 68   // fbuf dword stride (16B-aligned float4 rows)
#define ZST 66   // zbuf elem stride (8B-aligned packed writes)
#define RST 36   // reduce dword row stride: quad -> 16*quad mod 32, 2-way = free

#define GLOAD_LDS16(gp, lp) \
    __builtin_amdgcn_global_load_lds((const __attribute__((address_space(1))) void*)(gp), \
                                     (__attribute__((address_space(3))) void*)(lp), 16, 0, 0)

__device__ __forceinline__ unsigned bf16bits(float x) {
    __hip_bfloat16 h = __float2bfloat16(x);
    return (unsigned)*(unsigned short*)&h;
}

// ---------------------------------------------------------------------------
// Kernel 1: transpose (+ double scan for the pre side), float4 global loads.
// grid (32, 16, 2), block 256 (4 waves). z=0: post -> AT, z=1: pre -> BT.
// zbuf overlays fbuf.  LDS 34816 B -> 4 blocks/CU.  (~12 us, near HBM floor)
// ---------------------------------------------------------------------------
__global__ __launch_bounds__(256, 4) void trace_kernel(
    const float* __restrict__ pre,
    const float* __restrict__ post,
    const int* __restrict__ dtp,
    __hip_bfloat16* __restrict__ AT,
    __hip_bfloat16* __restrict__ BT)
{
    __shared__ float fbuf[128 * FST];                    // 34816 B, t-major fp32
    __hip_bfloat16* zbuf = (__hip_bfloat16*)fbuf;        // overlay, t-major bf16

    const int tid = threadIdx.x;
    const int w   = tid >> 6;    // wave 0..3
    const int l   = tid & 63;
    const int nq  = tid & 15;    // float4 group along n
    const int tl  = tid >> 4;    // t-row within a 16-row pass
    const int n0  = blockIdx.x * 64;
    const int b   = blockIdx.y;
    const int a   = blockIdx.z;  // 0: post->AT, 1: pre->BT

    int di = dtp[0];
    float dtf = (di > 0 && di < 1000000) ? (float)di : *(const float*)dtp;
    const float decay = __expf(-dtf / 20.0f);

    if (a == 0) {
        #pragma unroll
        for (int pass = 0; pass < 8; ++pass) {
            const int t = pass * 16 + tl;
            float4 v = *(const float4*)&post[((size_t)b * 128 + t) * GN + n0 + 4 * nq];
            uint2 pk;
            pk.x = bf16bits(v.x) | (bf16bits(v.y) << 16);
            pk.y = bf16bits(v.z) | (bf16bits(v.w) << 16);
            *(uint2*)&zbuf[t * ZST + 4 * nq] = pk;
        }
        __syncthreads();
    } else {
        #pragma unroll
        for (int pass = 0; pass < 8; ++pass) {
            const int t = pass * 16 + tl;
            float4 v = *(const float4*)&pre[((size_t)b * 128 + t) * GN + n0 + 4 * nq];
            *(float4*)&fbuf[t * FST + 4 * nq] = v;
        }
        __syncthreads();

        const int t0 = 32 * w;   // this wave's t segment [t0, t0+32)
        float carry = 0.0f;
        #pragma unroll 8
        for (int t = 1; t < t0; ++t)
            carry = decay * carry + fbuf[t * FST + l];
        float z[32];
        #pragma unroll
        for (int j = 0; j < 32; ++j) {
            const int t = t0 + j;
            if (t >= 1) carry = decay * carry + fbuf[t * FST + l];
            z[j] = carry;                     // tr (t=0 -> 0)
        }
        float bc = 0.0f;
        #pragma unroll 8
        for (int t = 127; t >= t0 + 32; --t)
            bc = decay * bc + fbuf[t * FST + l];
        #pragma unroll
        for (int j = 31; j >= 0; --j) {
            const int t = t0 + j;
            bc = decay * bc + fbuf[t * FST + l];
            if (t >= 1) z[j] -= bc;           // Z = tr - rt   (Z[0] = 0)
        }
        __syncthreads();   // all waves done reading fbuf before zbuf overlay
        #pragma unroll
        for (int j = 0; j < 32; ++j)
            zbuf[(t0 + j) * ZST + l] = __float2bfloat16(z[j]);
        __syncthreads();
    }

    __hip_bfloat16* dst = (a == 0) ? AT : BT;
    #pragma unroll
    for (int j = 0; j < 4; ++j) {
        const int c  = tid + 256 * j;   // 0..1023
        const int n  = c >> 4;          // 0..63
        const int tc = c & 15;          // 8-t chunk
        unsigned int vv[8];
        #pragma unroll
        for (int i = 0; i < 8; ++i)
            vv[i] = *(const unsigned short*)&zbuf[(8 * tc + i) * ZST + n];
        uint4 pk;
        pk.x = vv[0] | (vv[1] << 16);
        pk.y = vv[2] | (vv[3] << 16);
        pk.z = vv[4] | (vv[5] << 16);
        pk.w = vv[6] | (vv[7] << 16);
        *(uint4*)(dst + (size_t)(n0 + n) * KTOT + b * 128 + tc * 8) = pk;
    }
}

// ---------------------------------------------------------------------------
// Kernel 2: out = 4w(1-w)*A_SCALE * (AT * BT^T), IN-BLOCK split-K,
// PIPELINED (T3 minimum-2-phase recipe, compiler-blessed barrier form):
//   BK 64 -> 32, each group's 24 KB region split into 2 ping-pong buffers
//   of 12 KB (A 8K + B 4K).  Per half-step: issue next half-tile's
//   global_load_lds FIRST, then ds_read + 8 MFMA on the current buffer,
//   THEN __syncthreads() (vmcnt(0)+lgkmcnt(0)+s_barrier).  Since this
//   pipeline drains vmcnt(0) at every barrier anyway (1-deep prefetch),
//   __syncthreads() is semantically identical to the asm vmcnt+s_barrier
//   pair but cannot be miscompiled/reordered.  The win vs the old loop is
//   the ORDER: old = barrier->stage->drain-barrier->compute (drain fully
//   exposed, 2 barriers/step); new = stage->compute->drain+barrier
//   (1 barrier/half-step, ~450 cyc of ds_read+MFMA issue covers the
//   ~200 cyc L2-hit staging latency; AT/BT are L2-resident per-XCD).
// LDS still 48 KB total -> 2 blocks/CU, 16 waves/CU (unchanged occupancy);
// barrier count unchanged (32/loop); K accumulation order is bit-identical
// to the BK=64 version, so absmax is unchanged.
// 4-slot XOR swizzle uses (row ^ (row>>2)) & 3: at the 64 B row stride this
// keeps ds_read_b128 2-way (free); plain row&3 would be 4-way (1.58x).
// XCD-chunked block swizzle (512 % 8 == 0, bijective): each XCD gets 64
// consecutive tiles = 2 full q-rows -> A panels (2 x 512 KB) stay L2-hot.
// Epilogue reduce unchanged (proven): group 1 parks acc at RST=36, group 0
// adds, applies softbound, writes.
// ---------------------------------------------------------------------------
__global__ __launch_bounds__(512, 4) void stdp_gemm(
    const __hip_bfloat16* __restrict__ AT,
    const __hip_bfloat16* __restrict__ BT,
    const float* __restrict__ W,
    float* __restrict__ out)
{
    __shared__ alignas(16) char smem[49152];   // 2 grp x 2 buf x 12288; reduce overlay

    const int tid  = threadIdx.x;
    const int lane = tid & 63;
    const int wv8  = tid >> 6;          // wave 0..7
    const int grp  = wv8 >> 2;          // K-half 0/1
    const int wv   = wv8 & 3;           // wave within group
    const int wm   = (wv >> 1) * 64;    // {0,64}
    const int wn   = (wv & 1) * 32;     // {0,32}

    // XCD-chunked swizzle: hw dispatch id -> contiguous 64-tile chunk per XCD
    const int hw   = blockIdx.y * 32 + blockIdx.x;
    const int tile = (hw & 7) * 64 + (hw >> 3);   // bijective (512 = 8*64)
    const int RM   = (tile >> 5) * 128;  // q base
    const int CN   = (tile & 31) * 64;   // p base

    const int l15  = lane & 15;
    const int quad = lane >> 4;

    char* base = smem + grp * 24576;     // this group's 2 ping-pong buffers

    const int K0 = grp * 1024;

    // Per-lane staging constants.  A: 128 rows x 4 chunks = 512 chunks over
    // (it, wv, lane); B: 64 rows x 4 chunks = 256 chunks over (wv, lane).
    // LDS slot (c&3) holds K-chunk (c&3)^swz(row); source is pre-swizzled.
    const int cA0   = wv * 64 + lane;                      // it=0, 0..255
    const int rowA0 = cA0 >> 2;                            // 0..63
    const int rowA1 = rowA0 + 64;                          // it=1, 64..127
    const int sl    = cA0 & 3;
    const int swzA0 = (rowA0 ^ (rowA0 >> 2)) & 3;
    const int swzA1 = (rowA1 ^ (rowA1 >> 2)) & 3;
    const __hip_bfloat16* srcA0 = AT + (size_t)(RM + rowA0) * KTOT + (sl ^ swzA0) * 8;
    const __hip_bfloat16* srcA1 = AT + (size_t)(RM + rowA1) * KTOT + (sl ^ swzA1) * 8;
    const __hip_bfloat16* srcB  = BT + (size_t)(CN + rowA0) * KTOT + (sl ^ swzA0) * 8;

    const int dA0 = wv * 1024;           // (wv*64 chunks)*16 B, wave-uniform
    const int dA1 = 4096 + wv * 1024;
    const int dB  = wv * 1024;

#define STAGE(buf, kofs) do {                                        \
        char* Ab_ = base + (buf) * 12288;                            \
        char* Bb_ = Ab_ + 8192;                                      \
        GLOAD_LDS16(srcA0 + (kofs), Ab_ + dA0);                      \
        GLOAD_LDS16(srcA1 + (kofs), Ab_ + dA1);                      \
        GLOAD_LDS16(srcB  + (kofs), Bb_ + dB);                       \
    } while (0)

    f32x4 acc[4][2] = {};

    // prologue: stage half-tile 0, drain, barrier
    STAGE(0, K0);
    __syncthreads();

    #pragma unroll 2
    for (int h = 0; h < 32; ++h) {
        const int cur = h & 1;
        if (h < 31) STAGE(cur ^ 1, K0 + (h + 1) * 32);   // prefetch next half

        const __hip_bfloat16* Ag = (const __hip_bfloat16*)(base + cur * 12288);
        const __hip_bfloat16* Bg = Ag + 4096;            // +8192 B

        bf16x8 af[4], bfr[2];
        #pragma unroll
        for (int i = 0; i < 4; ++i) {
            const int mr = wm + i * 16 + l15;
            af[i] = *(const bf16x8*)(Ag + mr * 32 + ((quad ^ ((mr ^ (mr >> 2)) & 3)) * 8));
        }
        #pragma unroll
        for (int j = 0; j < 2; ++j) {
            const int nr = wn + j * 16 + l15;
            bfr[j] = *(const bf16x8*)(Bg + nr * 32 + ((quad ^ ((nr ^ (nr >> 2)) & 3)) * 8));
        }
        #pragma unroll
        for (int i = 0; i < 4; ++i)
            #pragma unroll
            for (int j = 0; j < 2; ++j)
                acc[i][j] = __builtin_amdgcn_mfma_f32_16x16x32_bf16(
                    af[i], bfr[j], acc[i][j], 0, 0, 0);

        __syncthreads();   // drain this wave's stage (vmcnt 0) + block barrier
    }
#undef STAGE

    // -------- in-LDS split-K reduction + fused epilogue --------
    // C/D layout: acc[i][j][r] -> local row i*16+quad*4+r, local col j*16+l15
    float* red = (float*)smem;                 // 4 waves x 64 rows x RST dwords
    const int rbase = wv * 64 * RST;           // 9216 B/wave, 36864 B total
    if (grp == 1) {
        #pragma unroll
        for (int i = 0; i < 4; ++i)
            #pragma unroll
            for (int r = 0; r < 4; ++r)
                #pragma unroll
                for (int j = 0; j < 2; ++j)
                    red[rbase + (i * 16 + quad * 4 + r) * RST + j * 16 + l15] = acc[i][j][r];
    }
    __syncthreads();
    if (grp == 0) {
        #pragma unroll
        for (int i = 0; i < 4; ++i) {
            #pragma unroll
            for (int r = 0; r < 4; ++r) {
                const int q = RM + wm + i * 16 + quad * 4 + r;
                #pragma unroll
                for (int j = 0; j < 2; ++j) {
                    const int p = CN + wn + j * 16 + l15;
                    float v = acc[i][j][r]
                            + red[rbase + (i * 16 + quad * 4 + r) * RST + j * 16 + l15];
                    const float w  = W[(size_t)q * GN + p];
                    const float wf = 4.0f * w * (1.0f - w);
                    out[(size_t)q * GN + p] = wf * A_SCALE * v;
                }
            }
        }
    }
}

extern "C" void kernel_launch(void* const* d_in, const int* in_sizes, int n_in,
                              void* d_out, int out_size, void* d_ws, size_t ws_size,
                              hipStream_t stream) {
    const float* W    = (const float*)d_in[0];  // [2048][2048]
    const float* pre  = (const float*)d_in[1];  // [16][128][2048]
    const float* post = (const float*)d_in[2];  // [16][128][2048]
    const int*   dt   = (const int*)d_in[3];
    float* out = (float*)d_out;

    __hip_bfloat16* AT = (__hip_bfloat16*)d_ws;            // 8 MB
    __hip_bfloat16* BT = AT + (size_t)GN * KTOT;           // +8 MB

    trace_kernel<<<dim3(32, 16, 2), 256, 0, stream>>>(pre, post, dt, AT, BT);
    stdp_gemm<<<dim3(32, 16), 512, 0, stream>>>(AT, BT, W, out);
}